// Round 8
// baseline (194.719 us; speedup 1.0000x reference)
//
#include <hip/hip_runtime.h>
#include <stdint.h>

typedef __bf16 bf16;
typedef __attribute__((ext_vector_type(8))) __bf16 bf16x8;
typedef __attribute__((ext_vector_type(4))) __bf16 bf16x4;
typedef __attribute__((ext_vector_type(4))) float  f32x4;

#define ATT_SCALE 0.125f   // 1/sqrt(64), folded into Q at GEMM epilogue

// ---------------------------------------------------------------------------
// async 16B global -> LDS (wave-uniform LDS base + lane*16, per-lane gaddr)
// ---------------------------------------------------------------------------
__device__ __forceinline__ void async16(void* lds, const void* g) {
  __builtin_amdgcn_global_load_lds(
      (__attribute__((address_space(1))) void*)(void*)g,
      (__attribute__((address_space(3))) void*)lds,
      16, 0, 0);
}

// ---------------------------------------------------------------------------
// fp32 -> bf16 convert, 8 elems/thread
// ---------------------------------------------------------------------------
__global__ void convert_x_kernel(const float* __restrict__ x, bf16* __restrict__ y) {
  size_t i = ((size_t)blockIdx.x * 256 + threadIdx.x) * 8;
  float4 a = *(const float4*)(x + i);
  float4 b = *(const float4*)(x + i + 4);
  bf16x8 o;
  o[0] = (bf16)a.x; o[1] = (bf16)a.y; o[2] = (bf16)a.z; o[3] = (bf16)a.w;
  o[4] = (bf16)b.x; o[5] = (bf16)b.y; o[6] = (bf16)b.z; o[7] = (bf16)b.w;
  *(bf16x8*)(y + i) = o;
}

// ---------------------------------------------------------------------------
// W [768 x 2304] fp32  ->  Wt [2304 x 768] bf16  (LDS tiled transpose)
// ---------------------------------------------------------------------------
__global__ void transpose_w_kernel(const float* __restrict__ W, bf16* __restrict__ Wt) {
  __shared__ float tile[32][33];
  int tx = threadIdx.x, ty = threadIdx.y;
  int n0 = blockIdx.x * 32, k0 = blockIdx.y * 32;
#pragma unroll
  for (int r = 0; r < 4; ++r)
    tile[ty + r * 8][tx] = W[(size_t)(k0 + ty + r * 8) * 2304 + n0 + tx];
  __syncthreads();
#pragma unroll
  for (int r = 0; r < 4; ++r)
    Wt[(size_t)(n0 + ty + r * 8) * 768 + k0 + tx] = (bf16)tile[tx][ty + r * 8];
}

// ---------------------------------------------------------------------------
// QKV GEMM: C[8192 x 2304] = A[8192 x 768] * Wt^T + bias
//   Tile 128x128, BK=64, double-buffered LDS (2x32KB), one barrier per iter.
//   Line-coalesced DMA staging (8 rows x one aligned 128B line per instr)
//   with XOR swizzle (stored chunk = global chunk ^ (row&7)) -> frag
//   ds_read_b128s conflict-free. At structure plateau (~44us; LDS-BW-bound:
//   ~1150 cyc LDS vs ~155 cyc MFMA per block-iter).
// ---------------------------------------------------------------------------
__global__ void qkv_gemm_kernel(const bf16* __restrict__ A, const bf16* __restrict__ Bw,
                                const float* __restrict__ bias,
                                bf16* __restrict__ Qo, bf16* __restrict__ Ko,
                                bf16* __restrict__ Vo) {
  __shared__ __align__(16) char lds[65536];   // 2 x (A 16KB + B 16KB)

  const int tid  = threadIdx.x;
  const int wave = tid >> 6, lane = tid & 63;
  const int quad = lane >> 4, mn = lane & 15;
  const int wr = wave >> 1, wc = wave & 1;
  const int m0 = blockIdx.y * 128;
  const int n0 = blockIdx.x * 128;

  f32x4 acc[4][4] = {};

  const int lrow = lane >> 3;           // 0..7  (row within 8-row group)
  const int cg   = (lane & 7) ^ lrow;   // global 16B-chunk index (swizzled)

  auto stage = [&](int kt, char* buf) {
    char* Al = buf;
    char* Bl = buf + 16384;
#pragma unroll
    for (int u = 0; u < 4; ++u) {
      const int t   = wave * 4 + u;      // 8-row group 0..15
      const int row = t * 8 + lrow;      // tile row 0..127
      async16(Al + t * 1024 + lane * 16,
              A  + (size_t)(m0 + row) * 768 + kt + cg * 8);
      async16(Bl + t * 1024 + lane * 16,
              Bw + (size_t)(n0 + row) * 768 + kt + cg * 8);
    }
  };

  stage(0, lds);
  int p = 0;
  for (int kt = 0; kt < 768; kt += 64) {
    __syncthreads();                     // drains DMA into buf p
    if (kt + 64 < 768) stage(kt + 64, lds + (p ^ 1) * 32768);  // prefetch
    char* Al = lds + p * 32768;
    char* Bl = Al + 16384;

#pragma unroll
    for (int s = 0; s < 2; ++s) {        // two K=32 steps within BK=64
      bf16x8 af[4], bfr[4];
      const int csw = ((s * 4 + quad) ^ (mn & 7)) * 16;  // swizzled chunk offset
#pragma unroll
      for (int i = 0; i < 4; ++i) {
        af[i]  = *(const bf16x8*)(Al + (wr * 64 + i * 16 + mn) * 128 + csw);
        bfr[i] = *(const bf16x8*)(Bl + (wc * 64 + i * 16 + mn) * 128 + csw);
      }
#pragma unroll
      for (int i = 0; i < 4; ++i)
#pragma unroll
        for (int j = 0; j < 4; ++j)
          acc[i][j] = __builtin_amdgcn_mfma_f32_16x16x32_bf16(af[i], bfr[j], acc[i][j], 0, 0, 0);
    }
    p ^= 1;
  }

  // epilogue
  const int ng    = n0 + wc * 64;
  const int third = ng / 768;           // 0=Q 1=K 2=V
  const int nmod  = ng % 768;
  const float sc  = (third == 0) ? ATT_SCALE : 1.0f;
#pragma unroll
  for (int ct = 0; ct < 4; ++ct) {
    int n = nmod + ct * 16 + mn;
    int h = n >> 6, d = n & 63;
    float bv = bias[third * 768 + n];
#pragma unroll
    for (int rt = 0; rt < 4; ++rt) {
      int m  = m0 + wr * 64 + rt * 16 + quad * 4;
      int b  = m >> 10, t0 = m & 1023;
      size_t bh = (size_t)b * 12 + h;
      if (third == 2) {
        bf16x4 pk;
#pragma unroll
        for (int r = 0; r < 4; ++r) pk[r] = (bf16)(acc[rt][ct][r] + bv);
        *(bf16x4*)(Vo + (bh * 64 + d) * 1024 + t0) = pk;   // V^T
      } else {
        bf16* dst = (third == 0 ? Qo : Ko) + (bh * 1024 + t0) * 64 + d;
#pragma unroll
        for (int r = 0; r < 4; ++r) dst[(size_t)r * 64] = (bf16)((acc[rt][ct][r] + bv) * sc);
      }
    }
  }
}

// ---------------------------------------------------------------------------
// Attention v4 — BARRIER-FREE. K/V fragments loaded directly global->VGPR in
//   MFMA layout (no LDS staging of K/V at all); one-tile register lookahead
//   via unroll-by-2 ping-pong. Only LDS use is the wave-private S^T->A-layout
//   round trip (b64 writes / b128 reads, no barrier needed). Waves fully
//   decoupled: per-wave s_waitcnt, per-wave causal skip, balanced Q-tile
//   pairs (qta = y, qtb = 15-y share the KV stream; 17 tile-computations
//   per block). LDS 18KB; K/V tiles (16KB) L1-resident so waves 2..4 of a
//   block hit L1 on the redundant fragment loads.
// ---------------------------------------------------------------------------
__global__ __launch_bounds__(256, 2)
void attn_kernel(const bf16* __restrict__ Q, const bf16* __restrict__ K,
                 const bf16* __restrict__ Vt, float* __restrict__ out) {
  __shared__ __align__(16) char ldsS[18432];   // 128 rows x 144B

  const int tid  = threadIdx.x;
  const int wave = tid >> 6, lane = tid & 63;
  const int quad = lane >> 4, mn = lane & 15;
  const int bh  = blockIdx.x;
  const int qta = blockIdx.y;            // 0..7
  const int qtb = 15 - qta;              // 8..15
  const int qa0 = qta * 64, qb0 = qtb * 64;

  const bf16* Qg  = Q  + (size_t)bh * 65536;
  const bf16* Kg0 = K  + (size_t)bh * 65536;
  const bf16* Vg0 = Vt + (size_t)bh * 65536;

  // Q fragments: lane mn -> row base+mn, d = quad*8.. / 32+quad*8..
  bf16x8 qfA[2], qfB[2];
  {
    const bf16* ra = Qg + (size_t)(qa0 + wave * 16 + mn) * 64;
    qfA[0] = *(const bf16x8*)(ra + quad * 8);
    qfA[1] = *(const bf16x8*)(ra + 32 + quad * 8);
    const bf16* rb = Qg + (size_t)(qb0 + wave * 16 + mn) * 64;
    qfB[0] = *(const bf16x8*)(rb + quad * 8);
    qfB[1] = *(const bf16x8*)(rb + 32 + quad * 8);
  }

  f32x4 yA[4] = {}, yB[4] = {};

  // K frag: lane mn -> kk-row ct*16+mn, d = h*32+quad*8  (K rows 128B)
  // V frag: lane mn -> d-row  ct*16+mn, t = kb*32+quad*8 (Vt rows 2KB)
  auto loadT = [&](int j, bf16x8 (&kf)[4][2], bf16x8 (&vf)[4][2]) {
    const bf16* Kj = Kg0 + (size_t)j * 4096;
    const bf16* Vj = Vg0 + j * 64;
#pragma unroll
    for (int ct = 0; ct < 4; ++ct) {
      const bf16* kr = Kj + (ct * 16 + mn) * 64 + quad * 8;
      kf[ct][0] = *(const bf16x8*)(kr);
      kf[ct][1] = *(const bf16x8*)(kr + 32);
      const bf16* vr = Vj + (size_t)(ct * 16 + mn) * 1024 + quad * 8;
      vf[ct][0] = *(const bf16x8*)(vr);
      vf[ct][1] = *(const bf16x8*)(vr + 32);
    }
  };

  auto compute = [&](const bf16x8 (&kf)[4][2], const bf16x8 (&vf)[4][2], int j) {
    auto do_half = [&](const bf16x8* qf, f32x4* y, int half, int qrow, bool diag) {
      // S^T = K Q^T: lane holds (kk = j*64+ct*16+quad*4+r, q = qrow=base+mn)
#pragma unroll
      for (int ct = 0; ct < 4; ++ct) {
        f32x4 a = {};
        a = __builtin_amdgcn_mfma_f32_16x16x32_bf16(kf[ct][0], qf[0], a, 0, 0, 0);
        a = __builtin_amdgcn_mfma_f32_16x16x32_bf16(kf[ct][1], qf[1], a, 0, 0, 0);
        const int kkg = j * 64 + ct * 16 + quad * 4;
        bf16x4 pk;
#pragma unroll
        for (int r = 0; r < 4; ++r) {
          float v = a[r];
          v = v > 0.f ? v : 0.f;
          if (diag && kkg + r > qrow) v = 0.f;
          pk[r] = (bf16)v;
        }
        *(bf16x4*)(ldsS + (half * 64 + wave * 16 + mn) * 144 + (ct * 16 + quad * 4) * 2) = pk;
      }
      // Y += S V   (S read back in A-layout; rows wave-private, no barrier)
#pragma unroll
      for (int kb = 0; kb < 2; ++kb) {
        bf16x8 sf = *(const bf16x8*)(ldsS + (half * 64 + wave * 16 + mn) * 144 + kb * 64 + quad * 16);
#pragma unroll
        for (int ct = 0; ct < 4; ++ct)
          y[ct] = __builtin_amdgcn_mfma_f32_16x16x32_bf16(sf, vf[ct][kb], y[ct], 0, 0, 0);
      }
    };
    if (j <= qta) do_half(qfA, yA, 0, qa0 + wave * 16 + mn, j == qta);
    do_half(qfB, yB, 1, qb0 + wave * 16 + mn, j == qtb);
  };

  bf16x8 kfA[4][2], vfA[4][2], kfB[4][2], vfB[4][2];
  loadT(0, kfA, vfA);
  for (int jj = 0; jj <= qtb; jj += 2) {
    if (jj + 1 <= qtb) loadT(jj + 1, kfB, vfB);   // prefetch odd tile
    compute(kfA, vfA, jj);
    if (jj + 1 <= qtb) {
      if (jj + 2 <= qtb) loadT(jj + 2, kfA, vfA); // prefetch next even tile
      compute(kfB, vfB, jj + 1);
    }
  }

  // write out: out[b][t][h*64+d]; yacc: q = wave*16+quad*4+r, d = ct*16+mn
  const int b = bh / 12, h = bh % 12;
  {
    float* ob = out + ((size_t)b * 1024 + qa0 + wave * 16 + quad * 4) * 768 + h * 64;
#pragma unroll
    for (int ct = 0; ct < 4; ++ct)
#pragma unroll
      for (int r = 0; r < 4; ++r)
        ob[(size_t)r * 768 + ct * 16 + mn] = yA[ct][r];
  }
  {
    float* ob = out + ((size_t)b * 1024 + qb0 + wave * 16 + quad * 4) * 768 + h * 64;
#pragma unroll
    for (int ct = 0; ct < 4; ++ct)
#pragma unroll
      for (int r = 0; r < 4; ++r)
        ob[(size_t)r * 768 + ct * 16 + mn] = yB[ct][r];
  }
}

// ---------------------------------------------------------------------------
extern "C" void kernel_launch(void* const* d_in, const int* in_sizes, int n_in,
                              void* d_out, int out_size, void* d_ws, size_t ws_size,
                              hipStream_t stream) {
  const float* x    = (const float*)d_in[0];   // [8,1024,768]
  const float* W    = (const float*)d_in[1];   // [768,2304]
  const float* bias = (const float*)d_in[2];   // [2304]
  float* out = (float*)d_out;                  // [8,1024,768]

  char* ws = (char*)d_ws;
  bf16* xb = (bf16*)(ws);                      // 8192*768
  bf16* Wt = (bf16*)(ws + 12582912);           // 2304*768
  bf16* Qb = (bf16*)(ws + 16121856);           // 96*1024*64
  bf16* Kb = (bf16*)(ws + 28704768);           // 96*1024*64
  bf16* Vb = (bf16*)(ws + 41287680);           // 96*64*1024 (V^T)

  convert_x_kernel<<<3072, 256, 0, stream>>>(x, xb);
  transpose_w_kernel<<<dim3(72, 24), dim3(32, 8), 0, stream>>>(W, Wt);
  qkv_gemm_kernel<<<dim3(18, 64), 256, 0, stream>>>(xb, Wt, bias, Qb, Kb, Vb);
  attn_kernel<<<dim3(96, 8), 256, 0, stream>>>(Qb, Kb, Vb, out);
}

// Round 9
// 145.802 us; speedup vs baseline: 1.3355x; 1.3355x over previous
//
#include <hip/hip_runtime.h>
#include <stdint.h>

typedef __bf16 bf16;
typedef __attribute__((ext_vector_type(8))) __bf16 bf16x8;
typedef __attribute__((ext_vector_type(4))) __bf16 bf16x4;
typedef __attribute__((ext_vector_type(4))) float  f32x4;

#define ATT_SCALE 0.125f   // 1/sqrt(64), folded into Q at GEMM epilogue

// ---------------------------------------------------------------------------
// async 16B global -> LDS (wave-uniform LDS base + lane*16, per-lane gaddr)
// ---------------------------------------------------------------------------
__device__ __forceinline__ void async16(void* lds, const void* g) {
  __builtin_amdgcn_global_load_lds(
      (__attribute__((address_space(1))) void*)(void*)g,
      (__attribute__((address_space(3))) void*)lds,
      16, 0, 0);
}

// ---------------------------------------------------------------------------
// Fused prep: blocks [0,3072) convert x fp32->bf16 (8 elems/thread);
//             blocks [3072,4800) transpose W [768x2304] fp32 -> Wt bf16.
// ---------------------------------------------------------------------------
__global__ void prep_kernel(const float* __restrict__ x, bf16* __restrict__ y,
                            const float* __restrict__ W, bf16* __restrict__ Wt) {
  __shared__ float tile[32][33];
  const int tid = threadIdx.x;
  if (blockIdx.x < 3072) {
    size_t i = ((size_t)blockIdx.x * 256 + tid) * 8;
    float4 a = *(const float4*)(x + i);
    float4 b = *(const float4*)(x + i + 4);
    bf16x8 o;
    o[0] = (bf16)a.x; o[1] = (bf16)a.y; o[2] = (bf16)a.z; o[3] = (bf16)a.w;
    o[4] = (bf16)b.x; o[5] = (bf16)b.y; o[6] = (bf16)b.z; o[7] = (bf16)b.w;
    *(bf16x8*)(y + i) = o;
  } else {
    const int bid = blockIdx.x - 3072;        // 0..1727
    const int tx = tid & 31, ty = tid >> 5;   // 32 x 8
    const int n0 = (bid % 72) * 32, k0 = (bid / 72) * 32;
#pragma unroll
    for (int r = 0; r < 4; ++r)
      tile[ty + r * 8][tx] = W[(size_t)(k0 + ty + r * 8) * 2304 + n0 + tx];
    __syncthreads();
#pragma unroll
    for (int r = 0; r < 4; ++r)
      Wt[(size_t)(n0 + ty + r * 8) * 768 + k0 + tx] = (bf16)tile[tx][ty + r * 8];
  }
}

// ---------------------------------------------------------------------------
// QKV GEMM: C[8192 x 2304] = A[8192 x 768] * Wt^T + bias
//   Tile 128x128, BK=64, double-buffered LDS (2x32KB), one barrier per iter.
//   Line-coalesced DMA staging (8 rows x one aligned 128B line per instr)
//   with XOR swizzle (stored chunk = global chunk ^ (row&7)) -> frag
//   ds_read_b128s conflict-free. At structure plateau (~44us).
// ---------------------------------------------------------------------------
__global__ void qkv_gemm_kernel(const bf16* __restrict__ A, const bf16* __restrict__ Bw,
                                const float* __restrict__ bias,
                                bf16* __restrict__ Qo, bf16* __restrict__ Ko,
                                bf16* __restrict__ Vo) {
  __shared__ __align__(16) char lds[65536];   // 2 x (A 16KB + B 16KB)

  const int tid  = threadIdx.x;
  const int wave = tid >> 6, lane = tid & 63;
  const int quad = lane >> 4, mn = lane & 15;
  const int wr = wave >> 1, wc = wave & 1;
  const int m0 = blockIdx.y * 128;
  const int n0 = blockIdx.x * 128;

  f32x4 acc[4][4] = {};

  const int lrow = lane >> 3;           // 0..7  (row within 8-row group)
  const int cg   = (lane & 7) ^ lrow;   // global 16B-chunk index (swizzled)

  auto stage = [&](int kt, char* buf) {
    char* Al = buf;
    char* Bl = buf + 16384;
#pragma unroll
    for (int u = 0; u < 4; ++u) {
      const int t   = wave * 4 + u;      // 8-row group 0..15
      const int row = t * 8 + lrow;      // tile row 0..127
      async16(Al + t * 1024 + lane * 16,
              A  + (size_t)(m0 + row) * 768 + kt + cg * 8);
      async16(Bl + t * 1024 + lane * 16,
              Bw + (size_t)(n0 + row) * 768 + kt + cg * 8);
    }
  };

  stage(0, lds);
  int p = 0;
  for (int kt = 0; kt < 768; kt += 64) {
    __syncthreads();                     // drains DMA into buf p
    if (kt + 64 < 768) stage(kt + 64, lds + (p ^ 1) * 32768);  // prefetch
    char* Al = lds + p * 32768;
    char* Bl = Al + 16384;

#pragma unroll
    for (int s = 0; s < 2; ++s) {        // two K=32 steps within BK=64
      bf16x8 af[4], bfr[4];
      const int csw = ((s * 4 + quad) ^ (mn & 7)) * 16;  // swizzled chunk offset
#pragma unroll
      for (int i = 0; i < 4; ++i) {
        af[i]  = *(const bf16x8*)(Al + (wr * 64 + i * 16 + mn) * 128 + csw);
        bfr[i] = *(const bf16x8*)(Bl + (wc * 64 + i * 16 + mn) * 128 + csw);
      }
#pragma unroll
      for (int i = 0; i < 4; ++i)
#pragma unroll
        for (int j = 0; j < 4; ++j)
          acc[i][j] = __builtin_amdgcn_mfma_f32_16x16x32_bf16(af[i], bfr[j], acc[i][j], 0, 0, 0);
    }
    p ^= 1;
  }

  // epilogue
  const int ng    = n0 + wc * 64;
  const int third = ng / 768;           // 0=Q 1=K 2=V
  const int nmod  = ng % 768;
  const float sc  = (third == 0) ? ATT_SCALE : 1.0f;
#pragma unroll
  for (int ct = 0; ct < 4; ++ct) {
    int n = nmod + ct * 16 + mn;
    int h = n >> 6, d = n & 63;
    float bv = bias[third * 768 + n];
#pragma unroll
    for (int rt = 0; rt < 4; ++rt) {
      int m  = m0 + wr * 64 + rt * 16 + quad * 4;
      int b  = m >> 10, t0 = m & 1023;
      size_t bh = (size_t)b * 12 + h;
      if (third == 2) {
        bf16x4 pk;
#pragma unroll
        for (int r = 0; r < 4; ++r) pk[r] = (bf16)(acc[rt][ct][r] + bv);
        *(bf16x4*)(Vo + (bh * 64 + d) * 1024 + t0) = pk;   // V^T
      } else {
        bf16* dst = (third == 0 ? Qo : Ko) + (bh * 1024 + t0) * 64 + d;
#pragma unroll
        for (int r = 0; r < 4; ++r) dst[(size_t)r * 64] = (bf16)((acc[rt][ct][r] + bv) * sc);
      }
    }
  }
}

// ---------------------------------------------------------------------------
// Attention v5 = v3 (best measured) + conflict-free S buffer + phase split.
//   Block (bh, y): Q-tiles qta = y and qtb = 15-qta share one KV stream
//   j = 0..qtb. KV tiles DMA'd (XOR swizzle) into double-buffered LDS; one
//   barrier per iter. QK as mfma(kf,qf)=S^T -> b64 S-writes.
//   S buffer: pitch 128B, 8B-chunk XOR swizzle (stored c8 = c8 ^ ((mn&7)<<1),
//   preserving 16B read-pair contiguity) -> S writes & reads <=2-way (free).
//   Phase split per iter: QK(A), QK(B), then SV(A), SV(B) -- B's QK MFMAs
//   cover A's S round-trip latency. S rows wave-private (no barrier).
// ---------------------------------------------------------------------------
__global__ __launch_bounds__(256, 3)
void attn_kernel(const bf16* __restrict__ Q, const bf16* __restrict__ K,
                 const bf16* __restrict__ Vt, float* __restrict__ out) {
  __shared__ __align__(16) char lds[49152];
  // buf p at lds + p*16384: K 64x128B, then V 64x128B (both XOR-swizzled)
  char* ldsS = lds + 32768;              // 128 rows x 128B (A-half, B-half)

  const int tid  = threadIdx.x;
  const int wave = tid >> 6, lane = tid & 63;
  const int quad = lane >> 4, mn = lane & 15;
  const int bh  = blockIdx.x;
  const int qta = blockIdx.y;            // 0..7
  const int qtb = 15 - qta;              // 8..15
  const int qa0 = qta * 64, qb0 = qtb * 64;

  const bf16* Qg  = Q  + (size_t)bh * 65536;
  const bf16* Kg0 = K  + (size_t)bh * 65536;
  const bf16* Vg0 = Vt + (size_t)bh * 65536;

  // Q fragments: lane mn -> row base+mn, d = quad*8.. / 32+quad*8..
  bf16x8 qfA[2], qfB[2];
  {
    const bf16* ra = Qg + (size_t)(qa0 + wave * 16 + mn) * 64;
    qfA[0] = *(const bf16x8*)(ra + quad * 8);
    qfA[1] = *(const bf16x8*)(ra + 32 + quad * 8);
    const bf16* rb = Qg + (size_t)(qb0 + wave * 16 + mn) * 64;
    qfB[0] = *(const bf16x8*)(rb + quad * 8);
    qfB[1] = *(const bf16x8*)(rb + 32 + quad * 8);
  }

  f32x4 yA[4] = {}, yB[4] = {};

  const int lrow = lane >> 3;            // 0..7
  const int cg   = (lane & 7) ^ lrow;    // swizzled global chunk

  auto stageKV = [&](int j, char* buf) {
#pragma unroll
    for (int u2 = 0; u2 < 2; ++u2) {
      const int u   = wave * 2 + u2;     // 8-row group 0..7
      const int row = u * 8 + lrow;      // 0..63
      async16(buf + u * 1024 + lane * 16,
              Kg0 + (size_t)(j * 64 + row) * 64 + cg * 8);
      async16(buf + 8192 + u * 1024 + lane * 16,
              Vg0 + (size_t)row * 1024 + j * 64 + cg * 8);
    }
  };

  const int srow = (wave * 16 + mn) * 128;   // within a half (half adds 8192)

  stageKV(0, lds);
  for (int j = 0; j <= qtb; ++j) {
    __syncthreads();                     // drains DMA for buf j&1; WAR for j-2
    if (j < qtb) stageKV(j + 1, lds + ((j + 1) & 1) * 16384);
    char* bK = lds + (j & 1) * 16384;
    char* bV = bK + 8192;

    // hoisted K/V fragments (shared by both halves)
    bf16x8 kf[4][2], vf[4][2];
    const int sw = mn & 7;
#pragma unroll
    for (int ct = 0; ct < 4; ++ct) {
      const int ro = (ct * 16 + mn) * 128;
      kf[ct][0] = *(const bf16x8*)(bK + ro + ((quad)     ^ sw) * 16);
      kf[ct][1] = *(const bf16x8*)(bK + ro + ((4 + quad) ^ sw) * 16);
      vf[ct][0] = *(const bf16x8*)(bV + ro + ((quad)     ^ sw) * 16);
      vf[ct][1] = *(const bf16x8*)(bV + ro + ((4 + quad) ^ sw) * 16);
    }

    auto qk_half = [&](const bf16x8* qf, int half, int qrow, bool diag) {
      // S^T = K Q^T: lane holds (kk = j*64+ct*16+quad*4+r, q = qrow=base+mn)
#pragma unroll
      for (int ct = 0; ct < 4; ++ct) {
        f32x4 a = {};
        a = __builtin_amdgcn_mfma_f32_16x16x32_bf16(kf[ct][0], qf[0], a, 0, 0, 0);
        a = __builtin_amdgcn_mfma_f32_16x16x32_bf16(kf[ct][1], qf[1], a, 0, 0, 0);
        const int kkg = j * 64 + ct * 16 + quad * 4;
        bf16x4 pk;
#pragma unroll
        for (int r = 0; r < 4; ++r) {
          float v = a[r];
          v = v > 0.f ? v : 0.f;
          if (diag && kkg + r > qrow) v = 0.f;
          pk[r] = (bf16)v;
        }
        *(bf16x4*)(ldsS + half * 8192 + srow +
                   (((ct * 4 + quad) ^ (sw << 1)) & 15) * 8) = pk;
      }
    };
    auto sv_half = [&](f32x4* y, int half) {
#pragma unroll
      for (int kb = 0; kb < 2; ++kb) {
        bf16x8 sf = *(const bf16x8*)(ldsS + half * 8192 + srow +
                                     ((kb * 4 + quad) ^ sw) * 16);
#pragma unroll
        for (int ct = 0; ct < 4; ++ct)
          y[ct] = __builtin_amdgcn_mfma_f32_16x16x32_bf16(sf, vf[ct][kb], y[ct], 0, 0, 0);
      }
    };

    if (j <= qta) qk_half(qfA, 0, qa0 + wave * 16 + mn, j == qta);
    qk_half(qfB, 1, qb0 + wave * 16 + mn, j == qtb);
    if (j <= qta) sv_half(yA, 0);
    sv_half(yB, 1);
  }

  // write out: out[b][t][h*64+d]; yacc: q = wave*16+quad*4+r, d = ct*16+mn
  const int b = bh / 12, h = bh % 12;
  {
    float* ob = out + ((size_t)b * 1024 + qa0 + wave * 16 + quad * 4) * 768 + h * 64;
#pragma unroll
    for (int ct = 0; ct < 4; ++ct)
#pragma unroll
      for (int r = 0; r < 4; ++r)
        ob[(size_t)r * 768 + ct * 16 + mn] = yA[ct][r];
  }
  {
    float* ob = out + ((size_t)b * 1024 + qb0 + wave * 16 + quad * 4) * 768 + h * 64;
#pragma unroll
    for (int ct = 0; ct < 4; ++ct)
#pragma unroll
      for (int r = 0; r < 4; ++r)
        ob[(size_t)r * 768 + ct * 16 + mn] = yB[ct][r];
  }
}

// ---------------------------------------------------------------------------
extern "C" void kernel_launch(void* const* d_in, const int* in_sizes, int n_in,
                              void* d_out, int out_size, void* d_ws, size_t ws_size,
                              hipStream_t stream) {
  const float* x    = (const float*)d_in[0];   // [8,1024,768]
  const float* W    = (const float*)d_in[1];   // [768,2304]
  const float* bias = (const float*)d_in[2];   // [2304]
  float* out = (float*)d_out;                  // [8,1024,768]

  char* ws = (char*)d_ws;
  bf16* xb = (bf16*)(ws);                      // 8192*768
  bf16* Wt = (bf16*)(ws + 12582912);           // 2304*768
  bf16* Qb = (bf16*)(ws + 16121856);           // 96*1024*64
  bf16* Kb = (bf16*)(ws + 28704768);           // 96*1024*64
  bf16* Vb = (bf16*)(ws + 41287680);           // 96*64*1024 (V^T)

  prep_kernel<<<4800, 256, 0, stream>>>(x, xb, W, Wt);
  qkv_gemm_kernel<<<dim3(18, 64), 256, 0, stream>>>(xb, Wt, bias, Qb, Kb, Vb);
  attn_kernel<<<dim3(96, 8), 256, 0, stream>>>(Qb, Kb, Vb, out);
}